// Round 7
// baseline (441.236 us; speedup 1.0000x reference)
//
#include <hip/hip_runtime.h>

// EdgeNorm, round 11: r10 structure frozen; occupancy round.
//
// r10 post-mortem: 429us total, stats=114us at 31.7% occupancy (784 blocks
// = 3.06/CU, block-count-limited) and 1.7 TB/s on a latency-bound scattered
// 32B gather. FETCH arithmetic proved P=1 ran -> ws >= 124.1 MB proven.
// Scatter (unprofiled) ~220us by subtraction, also capped at 50% occ
// (1024 blocks = 4/CU).
//
// This round (no structural change):
//   stats  : 512-thread blocks (8 waves) + PARTS 4->8 -> ~100% wave occ.
//   scatter: CBLK 1024->2048 (chunk 1564) -> 8 blocks/CU = 100% wave occ.
//   ws     : ACCW 20->17 keeps P=1 need 123.7MB < 124.1MB proven floor.
//
// Measured walls (permanent): F1 random 64B-line full pass ~700GB/s ~290us;
// F2 17 scattered LDS atomics/edge ~310us. The bucket-sort pipeline is the
// only structure measured to dodge both.

#define NHEADS  8
#define KSHIFT  9
#define KNODES  512
#define NNODES  100000
#define NB      196           // ceil(100000/512)
#define CBLK    2048          // count/scatter blocks
#define CHMAX   1600          // max chunk (local edge idx fits 12 bits)
#define PARTS   8             // stats slices per bucket
#define SLMAX   2560          // max slice len (worst ~2105 at P=1)
#define ACCW    17            // nodeacc row: 8 sum | 8 sumsq | count

__global__ __launch_bounds__(256)
void count_kernel(const int* __restrict__ dst, unsigned* __restrict__ counts,
                  int p0, int p1, int chunk) {
    __shared__ unsigned hist[NB];
    for (int i = threadIdx.x; i < NB; i += 256) hist[i] = 0u;
    __syncthreads();
    const int blk = blockIdx.x;
    const int s0 = p0 + blk * chunk;
    const int s1 = min(s0 + chunk, p1);
    for (int i = s0 + (int)threadIdx.x * 4; i < s1; i += 256 * 4) {
        if (i + 4 <= s1) {
            int4 d = *reinterpret_cast<const int4*>(dst + i);
            atomicAdd(&hist[(unsigned)d.x >> KSHIFT], 1u);
            atomicAdd(&hist[(unsigned)d.y >> KSHIFT], 1u);
            atomicAdd(&hist[(unsigned)d.z >> KSHIFT], 1u);
            atomicAdd(&hist[(unsigned)d.w >> KSHIFT], 1u);
        } else {
            for (int j = i; j < s1; ++j)
                atomicAdd(&hist[(unsigned)dst[j] >> KSHIFT], 1u);
        }
    }
    __syncthreads();
    for (int b = threadIdx.x; b < NB; b += 256)
        counts[(size_t)b * CBLK + blk] = hist[b];
}

// One block per bucket: exclusive scan of counts[b][0..CBLK) in place.
// CBLK=2048 -> 8 elements per thread (two uint4).
__global__ __launch_bounds__(256)
void scan_kernel(unsigned* __restrict__ counts, unsigned* __restrict__ totals) {
    __shared__ unsigned sc[256];
    const int b = blockIdx.x;
    const size_t base = (size_t)b * CBLK + (size_t)threadIdx.x * 8;
    uint4 v0 = *reinterpret_cast<uint4*>(counts + base);
    uint4 v1 = *reinterpret_cast<uint4*>(counts + base + 4);
    unsigned s = v0.x + v0.y + v0.z + v0.w + v1.x + v1.y + v1.z + v1.w;
    sc[threadIdx.x] = s;
    __syncthreads();
    for (int off = 1; off < 256; off <<= 1) {
        unsigned t = (threadIdx.x >= (unsigned)off) ? sc[threadIdx.x - off] : 0u;
        __syncthreads();
        sc[threadIdx.x] += t;
        __syncthreads();
    }
    unsigned e = sc[threadIdx.x] - s;
    uint4 o0, o1;
    o0.x = e;            o0.y = o0.x + v0.x;
    o0.z = o0.y + v0.y;  o0.w = o0.z + v0.z;
    o1.x = o0.w + v0.w;  o1.y = o1.x + v1.x;
    o1.z = o1.y + v1.y;  o1.w = o1.z + v1.z;
    *reinterpret_cast<uint4*>(counts + base) = o0;
    *reinterpret_cast<uint4*>(counts + base + 4) = o1;
    if (threadIdx.x == 255) totals[b] = sc[255];
}

// Single block: exclusive prefix over bucket totals -> compact bucket bases.
__global__ __launch_bounds__(256)
void base_kernel(const unsigned* __restrict__ totals, unsigned* __restrict__ base) {
    __shared__ unsigned sc[256];
    unsigned v = (threadIdx.x < NB) ? totals[threadIdx.x] : 0u;
    sc[threadIdx.x] = v;
    __syncthreads();
    for (int off = 1; off < 256; off <<= 1) {
        unsigned t = (threadIdx.x >= (unsigned)off) ? sc[threadIdx.x - off] : 0u;
        __syncthreads();
        sc[threadIdx.x] += t;
        __syncthreads();
    }
    if (threadIdx.x < NB) base[threadIdx.x] = sc[threadIdx.x] - v;
}

// Local counting sort of the chunk by bucket, then coalesced payload emit.
// ord[] entry: local edge idx (12b) | node-in-bucket (9b, <<12) | bucket (<<21)
__global__ __launch_bounds__(256)
void scatter_kernel(const int* __restrict__ dst,
                    const unsigned* __restrict__ counts,
                    const unsigned* __restrict__ base,
                    const float* __restrict__ scores,
                    float* __restrict__ payload,
                    unsigned short* __restrict__ nidx,
                    int p0, int p1, int chunk, unsigned capE) {
    __shared__ unsigned hist[256];      // padded to 256 for the scan
    __shared__ unsigned pfx[NB];        // local exclusive prefix
    __shared__ unsigned lofs[NB];       // running local offsets
    __shared__ unsigned gbase[NB];      // global dest base for this block's run
    __shared__ unsigned ord[CHMAX];
    const int blk = blockIdx.x;
    const int s0 = p0 + blk * chunk;
    const int s1 = min(s0 + chunk, p1);
    const int n  = s1 - s0;

    hist[threadIdx.x] = 0u;
    __syncthreads();
    // phase 1: local histogram
    for (int i = s0 + (int)threadIdx.x * 4; i < s1; i += 256 * 4) {
        if (i + 4 <= s1) {
            int4 d = *reinterpret_cast<const int4*>(dst + i);
            atomicAdd(&hist[(unsigned)d.x >> KSHIFT], 1u);
            atomicAdd(&hist[(unsigned)d.y >> KSHIFT], 1u);
            atomicAdd(&hist[(unsigned)d.z >> KSHIFT], 1u);
            atomicAdd(&hist[(unsigned)d.w >> KSHIFT], 1u);
        } else {
            for (int j = i; j < s1; ++j)
                atomicAdd(&hist[(unsigned)dst[j] >> KSHIFT], 1u);
        }
    }
    __syncthreads();
    // phase 2: in-place inclusive scan of hist -> exclusive pfx
    unsigned myc = hist[threadIdx.x];
    for (int off = 1; off < 256; off <<= 1) {
        unsigned t = (threadIdx.x >= (unsigned)off) ? hist[threadIdx.x - off] : 0u;
        __syncthreads();
        hist[threadIdx.x] += t;
        __syncthreads();
    }
    unsigned excl = hist[threadIdx.x] - myc;
    if (threadIdx.x < NB) {
        pfx[threadIdx.x]  = excl;
        lofs[threadIdx.x] = excl;
        gbase[threadIdx.x] =
            base[threadIdx.x] + counts[(size_t)threadIdx.x * CBLK + blk];
    }
    __syncthreads();
    // phase 3: bucket-order the chunk's edge ids in LDS
    for (int i = s0 + (int)threadIdx.x; i < s1; i += 256) {
        int d = dst[i];
        unsigned b = (unsigned)d >> KSHIFT;
        unsigned pos = atomicAdd(&lofs[b], 1u);
        if (pos < (unsigned)CHMAX)          // invariant: pos < n <= CHMAX
            ord[pos] = (unsigned)(i - s0) |
                       ((unsigned)(d & (KNODES - 1)) << 12) | (b << 21);
    }
    __syncthreads();
    // phase 4: emit payload in bucket order -> contiguous runs.
    // scores gather is a permutation within the chunk's ~50KB window (L2-hot).
    for (int p = (int)threadIdx.x; p < n; p += 256) {
        unsigned r = ord[p];
        int el       = (int)(r & 0xFFFu);
        unsigned nib = (r >> 12) & 0x1FFu;
        unsigned b   = r >> 21;
        unsigned gi  = gbase[b] + (unsigned)p - pfx[b];
        if (gi >= capE) continue;           // invariant: gi < pass edge count
        const float4* ps = reinterpret_cast<const float4*>(
            scores + (size_t)(s0 + el) * NHEADS);
        float4 x0 = ps[0], x1 = ps[1];
        float4* pd = reinterpret_cast<float4*>(payload + (size_t)gi * NHEADS);
        pd[0] = x0;
        pd[1] = x1;
        nidx[gi] = (unsigned short)nib;
    }
}

// Block (part,bucket), 512 threads = 8 waves: LDS counting-sort of the
// slice's nidx indices, then one WAVE per node: 64 lanes = 8 edges x 8
// heads, butterfly, single wave-wide atomicAdd into nodeacc[node][0..16].
__global__ __launch_bounds__(512)
void stats_kernel(const float* __restrict__ payload,
                  const unsigned short* __restrict__ nidx,
                  const unsigned* __restrict__ totals,
                  const unsigned* __restrict__ baseb,
                  float* __restrict__ nodeacc) {
    __shared__ unsigned hist[KNODES];
    __shared__ unsigned seg[KNODES + 1];
    __shared__ unsigned cur[KNODES];
    __shared__ unsigned sc[512];
    __shared__ unsigned short sidx[SLMAX];

    const int part  = blockIdx.x;
    const int b     = blockIdx.y;
    const int total = (int)totals[b];
    const int rs    = (int)baseb[b];
    const int sliceLen = (total + PARTS - 1) / PARTS;
    const int l0 = min(total, part * sliceLen);
    const int l1 = min(total, l0 + sliceLen);
    const int n  = l1 - l0;                 // uniform across block
    if (n <= 0) return;
    const int gs0 = rs + l0;                // global slice start

    const int tid = (int)threadIdx.x;
    if (tid < KNODES) hist[tid] = 0u;
    __syncthreads();
    // pass A: histogram of node-in-bucket over the slice
    for (int i = tid; i < n; i += 512) {
        if (i >= SLMAX) break;
        unsigned k = (unsigned)nidx[gs0 + i] & (KNODES - 1);
        atomicAdd(&hist[k], 1u);
    }
    __syncthreads();
    // exclusive scan of hist[512] with 512 threads
    unsigned v = hist[tid];
    sc[tid] = v;
    __syncthreads();
    for (int off = 1; off < 512; off <<= 1) {
        unsigned t = (tid >= off) ? sc[tid - off] : 0u;
        __syncthreads();
        sc[tid] += t;
        __syncthreads();
    }
    unsigned excl = sc[tid] - v;
    seg[tid] = excl;
    cur[tid] = excl;
    if (tid == 511) seg[KNODES] = sc[511];
    __syncthreads();
    // pass B: place slice-local indices in node-sorted order
    for (int i = tid; i < n; i += 512) {
        if (i >= SLMAX) break;
        unsigned k = (unsigned)nidx[gs0 + i] & (KNODES - 1);
        unsigned pos = atomicAdd(&cur[k], 1u);
        if (pos < (unsigned)SLMAX) sidx[pos] = (unsigned short)i;
    }
    __syncthreads();

    // wave-per-node register reduction (8 waves cover 512 nodes)
    const int wv   = tid >> 6;
    const int lane = tid & 63;
    const int grp  = lane >> 3;             // edge slot 0..7
    const int h    = lane & 7;              // head
    for (int k = wv; k < KNODES; k += 8) {
        int ss = (int)seg[k];
        int ee = (int)seg[k + 1];
        int cc = ee - ss;
        if (cc <= 0) continue;
        float sv = 0.f, sw = 0.f;
        for (int j = grp; j < cc; j += 8) {
            int li = (int)sidx[ss + j];
            float x = payload[(size_t)(gs0 + li) * NHEADS + h];
            sv += x;
            sw = fmaf(x, x, sw);
        }
        sv += __shfl_xor(sv, 8);  sw += __shfl_xor(sw, 8);
        sv += __shfl_xor(sv, 16); sw += __shfl_xor(sw, 16);
        sv += __shfl_xor(sv, 32); sw += __shfl_xor(sw, 32);
        int gnode = b * KNODES + k;
        if (lane < ACCW && gnode < NNODES) {
            float val = (lane < 8) ? sv : ((lane < 16) ? sw : (float)cc);
            atomicAdd(&nodeacc[(size_t)gnode * ACCW + lane], val);
        }
    }
}

// AB layout: per node 16 floats = one 64B line: [A(8) | B(8)].
__global__ __launch_bounds__(256)
void coeff_kernel(const float* __restrict__ nodeacc,
                  const float* __restrict__ gain,
                  const float* __restrict__ bias,
                  float* __restrict__ AB, int total) {
    int i = blockIdx.x * 256 + threadIdx.x;
    if (i >= total) return;
    int node = i >> 3, h = i & 7;
    const float* acc = nodeacc + (size_t)node * ACCW;
    float s = acc[h];
    float q = acc[8 + h];
    float c = acc[16];
    float cm   = fmaxf(c, 1.0f);                 // ref: sums / max(counts,1)
    float mean = s / cm;
    float var  = fmaxf(q - s * mean, 0.0f);      // one-pass variance, clamped
    float inv  = 1.0f / fmaxf(sqrtf(var / cm), 1e-5f);
    float a = gain[h] * inv;
    AB[(size_t)node * 16 + h]     = a;
    AB[(size_t)node * 16 + 8 + h] = fmaf(-a, mean, bias[h]);
}

__global__ __launch_bounds__(256)
void edge_out_kernel(const float* __restrict__ scores,
                     const int* __restrict__ dst,
                     const float* __restrict__ AB,
                     float* __restrict__ out,
                     int num_edges) {
    int e = blockIdx.x * 256 + threadIdx.x;
    if (e >= num_edges) return;
    int d = dst[e];
    const float4* px  = reinterpret_cast<const float4*>(scores + (size_t)e * NHEADS);
    const float4* pab = reinterpret_cast<const float4*>(AB + (size_t)d * 16);
    float4 x0 = px[0], x1 = px[1];
    float4 a0 = pab[0], a1 = pab[1];
    float4 b0 = pab[2], b1 = pab[3];
    float4 o0, o1;
    o0.x = fmaf(a0.x, x0.x, b0.x);
    o0.y = fmaf(a0.y, x0.y, b0.y);
    o0.z = fmaf(a0.z, x0.z, b0.z);
    o0.w = fmaf(a0.w, x0.w, b0.w);
    o1.x = fmaf(a1.x, x1.x, b1.x);
    o1.y = fmaf(a1.y, x1.y, b1.y);
    o1.z = fmaf(a1.z, x1.z, b1.z);
    o1.w = fmaf(a1.w, x1.w, b1.w);
    float4* po = reinterpret_cast<float4*>(out + (size_t)e * NHEADS);
    po[0] = o0;
    po[1] = o1;
}

// ---- global-atomic fallback (only if ws implausibly small) ----------------
__global__ void edge_stats_fallback(const float* __restrict__ scores,
                                    const int* __restrict__ dst,
                                    float* __restrict__ sums,
                                    float* __restrict__ sumsq,
                                    int* __restrict__ counts,
                                    int num_edges) {
    int e = blockIdx.x * blockDim.x + threadIdx.x;
    if (e >= num_edges) return;
    int d = dst[e];
    const float4* p = reinterpret_cast<const float4*>(scores + (size_t)e * NHEADS);
    float4 x0 = p[0], x1 = p[1];
    float* s = sums  + (size_t)d * NHEADS;
    float* q = sumsq + (size_t)d * NHEADS;
    atomicAdd(s + 0, x0.x); atomicAdd(s + 1, x0.y);
    atomicAdd(s + 2, x0.z); atomicAdd(s + 3, x0.w);
    atomicAdd(s + 4, x1.x); atomicAdd(s + 5, x1.y);
    atomicAdd(s + 6, x1.z); atomicAdd(s + 7, x1.w);
    atomicAdd(q + 0, x0.x * x0.x); atomicAdd(q + 1, x0.y * x0.y);
    atomicAdd(q + 2, x0.z * x0.z); atomicAdd(q + 3, x0.w * x0.w);
    atomicAdd(q + 4, x1.x * x1.x); atomicAdd(q + 5, x1.y * x1.y);
    atomicAdd(q + 6, x1.z * x1.z); atomicAdd(q + 7, x1.w * x1.w);
    atomicAdd(counts + d, 1);
}

__global__ void coeff_fallback(const float* __restrict__ sums,
                               const float* __restrict__ sumsq,
                               const int* __restrict__ counts,
                               const float* __restrict__ gain,
                               const float* __restrict__ bias,
                               float* __restrict__ AB, int total) {
    int i = blockIdx.x * blockDim.x + threadIdx.x;
    if (i >= total) return;
    int h = i & (NHEADS - 1);
    int node = i >> 3;
    float cm = fmaxf((float)counts[node], 1.0f);
    float s = sums[i];
    float mean = s / cm;
    float var_sum = fmaxf(sumsq[i] - s * mean, 0.0f);
    float inv = 1.0f / fmaxf(sqrtf(var_sum / cm), 1e-5f);
    float a = gain[h] * inv;
    AB[(size_t)node * 16 + h]     = a;
    AB[(size_t)node * 16 + 8 + h] = fmaf(-a, mean, bias[h]);
}
// ---------------------------------------------------------------------------

extern "C" void kernel_launch(void* const* d_in, const int* in_sizes, int n_in,
                              void* d_out, int out_size, void* d_ws, size_t ws_size,
                              hipStream_t stream) {
    const float* scores = (const float*)d_in[0];
    const float* gain   = (const float*)d_in[1];
    const float* bias   = (const float*)d_in[2];
    const int*   dst    = (const int*)d_in[3];

    const int E  = in_sizes[3];
    const int N  = NNODES;
    const int NH = N * NHEADS;
    const int B  = 256;

    // Fixed ws sections (256B-aligned):
    //   AB       : N*16 f32          6.40 MB
    //   counts   : NB*CBLK u32       1.61 MB
    //   totals   : NB u32   base : NB u32
    //   nodeacc  : N*ACCW f32        6.80 MB
    // Per-pass sections (P=1): payload 102.50 MB, nidx 6.41 MB.
    // Total P=1 ~= 123.7 MB  (< 124.1 MB floor proven by r10 running P=1).
    size_t off = 0;
    float* AB = (float*)d_ws;                          off += (size_t)N * 16 * 4;
    off = (off + 255) & ~(size_t)255;
    unsigned* counts = (unsigned*)((char*)d_ws + off); off += (size_t)NB * CBLK * 4;
    off = (off + 255) & ~(size_t)255;
    unsigned* totals = (unsigned*)((char*)d_ws + off); off += (size_t)NB * 4;
    off = (off + 255) & ~(size_t)255;
    unsigned* baseb  = (unsigned*)((char*)d_ws + off); off += (size_t)NB * 4;
    off = (off + 255) & ~(size_t)255;
    float* nodeacc   = (float*)((char*)d_ws + off);    off += (size_t)N * ACCW * 4;
    off = (off + 255) & ~(size_t)255;
    const size_t fixed = off;

    // Choose pass count: smallest P with chunk<=CHMAX and ws fit.
    int P = 0, chunk = 0;
    size_t payOff = 0, nixOff = 0;
    size_t passCap = 0;
    const int cand[4] = {1, 2, 4, 8};
    for (int ci = 0; ci < 4; ++ci) {
        int p = cand[ci];
        long long perPass = ((long long)E + p - 1) / p;
        long long ch = (((perPass + CBLK - 1) / CBLK) + 3) & ~3LL;
        if (ch > CHMAX) continue;
        size_t passE = (size_t)ch * CBLK;
        size_t po = fixed;
        size_t no = (po + passE * NHEADS * 4 + 255) & ~(size_t)255;
        size_t need = no + passE * 2;
        if (need <= ws_size) {
            P = p; chunk = (int)ch; payOff = po; nixOff = no; passCap = passE;
            break;
        }
    }

    if (P) {
        float* payload = (float*)((char*)d_ws + payOff);
        unsigned short* nidx = (unsigned short*)((char*)d_ws + nixOff);
        hipMemsetAsync(nodeacc, 0, (size_t)N * ACCW * 4, stream);
        for (int pass = 0; pass < P; ++pass) {
            int p0 = pass * chunk * CBLK;
            if (p0 >= E) break;
            int p1 = min(E, p0 + chunk * CBLK);
            count_kernel<<<CBLK, B, 0, stream>>>(dst, counts, p0, p1, chunk);
            scan_kernel<<<NB, B, 0, stream>>>(counts, totals);
            base_kernel<<<1, B, 0, stream>>>(totals, baseb);
            scatter_kernel<<<CBLK, B, 0, stream>>>(dst, counts, baseb, scores,
                                                   payload, nidx, p0, p1, chunk,
                                                   (unsigned)passCap);
            dim3 gs(PARTS, NB);
            stats_kernel<<<gs, 512, 0, stream>>>(payload, nidx, totals, baseb,
                                                 nodeacc);
        }
        coeff_kernel<<<(NH + B - 1) / B, B, 0, stream>>>(nodeacc, gain, bias, AB, NH);
        edge_out_kernel<<<(E + B - 1) / B, B, 0, stream>>>(scores, dst, AB,
                                                           (float*)d_out, E);
    } else {
        float* sums  = (float*)((char*)d_ws + (size_t)N * 16 * 4);
        float* sumsq = sums + NH;
        int*   cnts  = (int*)(sumsq + NH);
        hipMemsetAsync(sums, 0,
                       (size_t)(2 * NH) * sizeof(float) + (size_t)N * sizeof(int), stream);
        int blocks_e = (E + B - 1) / B;
        edge_stats_fallback<<<blocks_e, B, 0, stream>>>(scores, dst, sums, sumsq, cnts, E);
        coeff_fallback<<<(NH + B - 1) / B, B, 0, stream>>>(sums, sumsq, cnts, gain, bias, AB, NH);
        edge_out_kernel<<<blocks_e, B, 0, stream>>>(scores, dst, AB, (float*)d_out, E);
    }
}